// Round 4
// baseline (181.318 us; speedup 1.0000x reference)
//
#include <hip/hip_runtime.h>

// PGNN: N=50000 nodes, K=32 anchors/edges per node, E=1.6M edges
// out: normalize(out_position)[N,32] f32
constexpr int NN = 50000;
constexpr int KANCH = 32;

typedef __attribute__((ext_vector_type(8))) short bfrag;   // 8 bf16 (4 VGPR)
typedef __attribute__((ext_vector_type(4))) float ffrag;   // 4 f32 acc

static __device__ __forceinline__ float bf2f(unsigned short u) {
    return __uint_as_float(((unsigned int)u) << 16);
}
static __device__ __forceinline__ unsigned short f2bf(float f) {
    unsigned int x = __float_as_uint(f);
    x += 0x7FFFu + ((x >> 16) & 1u);   // round-to-nearest-even
    return (unsigned short)(x >> 16);
}

// ---------------------------------------------------------------------------
// K0: compose layer-1 weights through the pre-linear; pack weights to bf16.
// ---------------------------------------------------------------------------
__global__ __launch_bounds__(256) void k_prep(
    const float* __restrict__ w_pre, const float* __restrict__ b_pre,
    const float* __restrict__ Wu1, const float* __restrict__ bu1,
    const float* __restrict__ Wv1, const float* __restrict__ bv1,
    const float* __restrict__ Wu2, const float* __restrict__ bu2,
    const float* __restrict__ Wv2, const float* __restrict__ bv2,
    unsigned short* __restrict__ wcat1, float* __restrict__ bias1,
    unsigned short* __restrict__ wcat2, float* __restrict__ bias2)
{
    int gid = blockIdx.x * 256 + threadIdx.x;
    if (gid < 16384) {
        int j = gid >> 7, i = gid & 127;
        const float* Wr = (j < 64) ? (Wu1 + j * 64) : (Wv1 + (j - 64) * 64);
        float a = 0.f;
        for (int t = 0; t < 64; ++t) a += Wr[t] * w_pre[t * 128 + i];
        wcat1[gid] = f2bf(a);
    } else if (gid < 16384 + 4096) {
        int g = gid - 16384;
        int j = g >> 6, i = g & 63;
        float w = (j < 32) ? Wu2[j * 64 + i] : Wv2[(j - 32) * 64 + i];
        wcat2[g] = f2bf(w);
    } else if (gid < 16384 + 4096 + 128) {
        int j = gid - (16384 + 4096);
        const float* Wr = (j < 64) ? (Wu1 + j * 64) : (Wv1 + (j - 64) * 64);
        float a = (j < 64) ? bu1[j] : bv1[j - 64];
        for (int t = 0; t < 64; ++t) a += Wr[t] * b_pre[t];
        bias1[j] = a;
    } else if (gid < 16384 + 4096 + 128 + 64) {
        int j = gid - (16384 + 4096 + 128);
        bias2[j] = (j < 32) ? bu2[j] : bv2[j - 32];
    }
}

// ---------------------------------------------------------------------------
// K1: layer-1 u/v linears via MFMA, writing SLICE-MAJOR bf16 tables
// u1s/v1s[slice][NN][16] (slice = 16 output dims) for the L2-resident gather.
// A (feat f32) split in-register into bf16 hi+lo (exact; 2 MFMAs per step).
// ---------------------------------------------------------------------------
__global__ __launch_bounds__(256) void k_gemm1(
    const float* __restrict__ feat,            // [NN][128]
    const unsigned short* __restrict__ wcat,   // [128][128] bf16
    const float* __restrict__ bias,            // [128] f32
    unsigned short* __restrict__ u1s,          // [4][NN][16] bf16
    unsigned short* __restrict__ v1s,          // [4][NN][16] bf16
    int nTiles)                                // NN/16
{
    __shared__ unsigned short s_w[128 * 136];  // 272 B row stride
    __shared__ float s_b[128];
    int tid = threadIdx.x;
    for (int idx = tid; idx < 128 * 16; idx += 256) {
        int r = idx >> 4, c8 = idx & 15;
        const uint4* g = reinterpret_cast<const uint4*>(wcat + r * 128 + c8 * 8);
        *reinterpret_cast<uint4*>(&s_w[r * 136 + c8 * 8]) = *g;
    }
    if (tid < 128) s_b[tid] = bias[tid];
    __syncthreads();

    int wv = __builtin_amdgcn_readfirstlane(tid >> 6);
    int lane = tid & 63;
    int col = lane & 15;        // A row (node) / D col (out) / W row
    int grp = lane >> 4;        // k-subchunk 0..3
    int slot = blockIdx.x * 4 + wv;
    int stride = gridDim.x * 4;
    for (int tile = slot; tile < nTiles; tile += stride) {
        int n0 = tile * 16;
        const float* fp = feat + (size_t)(n0 + col) * 128 + grp * 8;
        bfrag AH[4], AL[4];
#pragma unroll
        for (int s = 0; s < 4; ++s) {
            float4 p0 = *reinterpret_cast<const float4*>(fp + s * 32);
            float4 p1 = *reinterpret_cast<const float4*>(fp + s * 32 + 4);
            float a8[8] = {p0.x, p0.y, p0.z, p0.w, p1.x, p1.y, p1.z, p1.w};
#pragma unroll
            for (int e = 0; e < 8; ++e) {
                unsigned short hb = f2bf(a8[e]);
                AH[s][e] = (short)hb;
                AL[s][e] = (short)f2bf(a8[e] - bf2f(hb));
            }
        }
#pragma unroll
        for (int t = 0; t < 8; ++t) {
            ffrag a = {0.f, 0.f, 0.f, 0.f};
#pragma unroll
            for (int s = 0; s < 4; ++s) {
                const bfrag w = *reinterpret_cast<const bfrag*>(
                    &s_w[(t * 16 + col) * 136 + s * 32 + grp * 8]);
                a = __builtin_amdgcn_mfma_f32_16x16x32_bf16(AH[s], w, a, 0, 0, 0);
                a = __builtin_amdgcn_mfma_f32_16x16x32_bf16(AL[s], w, a, 0, 0, 0);
            }
            float bb = s_b[t * 16 + col];
#pragma unroll
            for (int j = 0; j < 4; ++j) {
                int node = n0 + grp * 4 + j;
                unsigned short o = f2bf(a[j] + bb);
                if (t < 4) u1s[((size_t)t * NN + node) * 16 + col] = o;
                else       v1s[((size_t)(t - 4) * NN + node) * 16 + col] = o;
            }
        }
    }
}

// ---------------------------------------------------------------------------
// K2: layer-1 aggregation over ONE 16-dim slice. Per-pass gather working set
// = 2 x 1.6 MB table slices -> L2-resident per XCD. Indices are re-read each
// pass with NON-TEMPORAL loads so the stream doesn't evict the slice.
// lane = (es=lane>>2: 16 edges/instr, c=lane&3: ushort4 of slice dims).
// Wave covers 16 rows x 32 B = 512 B per table instruction.
// ---------------------------------------------------------------------------
__global__ __launch_bounds__(256) void k_gather1s(
    const ushort4* __restrict__ u1s, const ushort4* __restrict__ v1s, // [4*NN*4]
    const int* __restrict__ src, const int* __restrict__ dst,
    const float* __restrict__ dists, ushort4* __restrict__ x2v,      // [NN*16]
    int slice)
{
    int tid = threadIdx.x;
    int wv = __builtin_amdgcn_readfirstlane(tid >> 6);
    int lane = tid & 63;
    int c = lane & 3;       // slice dims 4c..4c+3
    int es = lane >> 2;     // edge subgroup 0..15
    int slot = blockIdx.x * 4 + wv;
    int stride = gridDim.x * 4;
    size_t tbase = (size_t)slice * NN * 4;   // slice base, in ushort4 units
    for (int n = slot; n < NN; n += stride) {
        int base = n * KANCH;
        float a0 = 0.f, a1 = 0.f, a2 = 0.f, a3 = 0.f;
#pragma unroll
        for (int kk = 0; kk < 2; ++kk) {
            int k = kk * 16 + es;
            int sk = __builtin_nontemporal_load(src + base + k);
            int dk = __builtin_nontemporal_load(dst + base + k);
            float sp = __builtin_nontemporal_load(dists + base + k);
            ushort4 uu = u1s[tbase + (size_t)sk * 4 + c];
            ushort4 vv = v1s[tbase + (size_t)dk * 4 + c];
            a0 += fmaxf(fmaf(bf2f(uu.x), sp, bf2f(vv.x)), 0.f);
            a1 += fmaxf(fmaf(bf2f(uu.y), sp, bf2f(vv.y)), 0.f);
            a2 += fmaxf(fmaf(bf2f(uu.z), sp, bf2f(vv.z)), 0.f);
            a3 += fmaxf(fmaf(bf2f(uu.w), sp, bf2f(vv.w)), 0.f);
        }
        // reduce over the 16 edge-subgroups (lane bits 2..5)
        a0 += __shfl_xor(a0, 4); a0 += __shfl_xor(a0, 8);
        a0 += __shfl_xor(a0, 16); a0 += __shfl_xor(a0, 32);
        a1 += __shfl_xor(a1, 4); a1 += __shfl_xor(a1, 8);
        a1 += __shfl_xor(a1, 16); a1 += __shfl_xor(a1, 32);
        a2 += __shfl_xor(a2, 4); a2 += __shfl_xor(a2, 8);
        a2 += __shfl_xor(a2, 16); a2 += __shfl_xor(a2, 32);
        a3 += __shfl_xor(a3, 4); a3 += __shfl_xor(a3, 8);
        a3 += __shfl_xor(a3, 16); a3 += __shfl_xor(a3, 32);
        if (lane < 4) {
            ushort4 r;
            r.x = f2bf(a0 * 0.03125f); r.y = f2bf(a1 * 0.03125f);
            r.z = f2bf(a2 * 0.03125f); r.w = f2bf(a3 * 0.03125f);
            x2v[(size_t)n * 16 + slice * 4 + lane] = r;   // x2b[n][64] layout
        }
    }
}

// ---------------------------------------------------------------------------
// K3: layer-2 u/v linears via MFMA.  [50000,64] bf16 @ [64,64]ᵀ bf16.
// ---------------------------------------------------------------------------
__global__ __launch_bounds__(256) void k_gemm2(
    const unsigned short* __restrict__ x2b,    // [NN][64] bf16
    const unsigned short* __restrict__ wcat,   // [64][64] bf16
    const float* __restrict__ bias,            // [64] f32
    unsigned short* __restrict__ ub,           // [NN][32] bf16
    unsigned short* __restrict__ vb,           // [NN][32] bf16
    int nTiles)
{
    __shared__ unsigned short s_w[64 * 72];
    __shared__ float s_b[64];
    int tid = threadIdx.x;
    for (int idx = tid; idx < 64 * 8; idx += 256) {
        int r = idx >> 3, c8 = idx & 7;
        const uint4* g = reinterpret_cast<const uint4*>(wcat + r * 64 + c8 * 8);
        *reinterpret_cast<uint4*>(&s_w[r * 72 + c8 * 8]) = *g;
    }
    if (tid < 64) s_b[tid] = bias[tid];
    __syncthreads();

    int wv = __builtin_amdgcn_readfirstlane(tid >> 6);
    int lane = tid & 63;
    int col = lane & 15;
    int grp = lane >> 4;
    int slot = blockIdx.x * 4 + wv;
    int stride = gridDim.x * 4;
    for (int tile = slot; tile < nTiles; tile += stride) {
        int n0 = tile * 16;
        bfrag A[2];
#pragma unroll
        for (int s = 0; s < 2; ++s) {
            uint4 raw = *reinterpret_cast<const uint4*>(
                x2b + (size_t)(n0 + col) * 64 + s * 32 + grp * 8);
            A[s] = *reinterpret_cast<const bfrag*>(&raw);
        }
#pragma unroll
        for (int t = 0; t < 4; ++t) {
            ffrag a = {0.f, 0.f, 0.f, 0.f};
#pragma unroll
            for (int s = 0; s < 2; ++s) {
                const bfrag w = *reinterpret_cast<const bfrag*>(
                    &s_w[(t * 16 + col) * 72 + s * 32 + grp * 8]);
                a = __builtin_amdgcn_mfma_f32_16x16x32_bf16(A[s], w, a, 0, 0, 0);
            }
            float bb = s_b[t * 16 + col];
#pragma unroll
            for (int j = 0; j < 4; ++j) {
                int node = n0 + grp * 4 + j;
                unsigned short o = f2bf(a[j] + bb);
                if (t < 2) ub[(size_t)node * 32 + t * 16 + col] = o;
                else       vb[(size_t)node * 32 + (t - 2) * 16 + col] = o;
            }
        }
    }
}

// ---------------------------------------------------------------------------
// K4: layer-2 message + position dot + L2 normalize. Wave-per-node.
// lane = (es=lane>>3, c=lane&7). ushort4 table reads (8 rows x 64 B / instr);
// per-edge dot via 3 shfl_xor; q-collection via indexed shfls; 5-shfl norm.
// Index loads non-temporal (protect the 6.4 MB u2/v2 tables in L2).
// ---------------------------------------------------------------------------
__global__ __launch_bounds__(256) void k_out(
    const ushort4* __restrict__ u2v, const ushort4* __restrict__ v2v,
    const int* __restrict__ src, const int* __restrict__ dst,
    const float* __restrict__ dists, const float* __restrict__ wp2,
    const float* __restrict__ bp2, float* __restrict__ out)
{
    int tid = threadIdx.x;
    int wv = __builtin_amdgcn_readfirstlane(tid >> 6);
    int lane = tid & 63;
    int c = lane & 7;       // dims 4c..4c+3
    int es = lane >> 3;     // edge subgroup 0..7
    int slot = blockIdx.x * 4 + wv;
    int stride = gridDim.x * 4;
    float4 w4 = reinterpret_cast<const float4*>(wp2)[c];
    float bp = bp2[0];
    for (int n = slot; n < NN; n += stride) {
        int base = n * KANCH;
        float q0, q1, q2, q3;
#pragma unroll
        for (int kk = 0; kk < 4; ++kk) {
            int k = kk * 8 + es;
            int sk = __builtin_nontemporal_load(src + base + k);
            int dk = __builtin_nontemporal_load(dst + base + k);
            float sp = __builtin_nontemporal_load(dists + base + k);
            ushort4 uu = u2v[(size_t)sk * 8 + c];
            ushort4 vv = v2v[(size_t)dk * 8 + c];
            float p;
            p  = fmaxf(fmaf(bf2f(uu.x), sp, bf2f(vv.x)), 0.f) * w4.x;
            p += fmaxf(fmaf(bf2f(uu.y), sp, bf2f(vv.y)), 0.f) * w4.y;
            p += fmaxf(fmaf(bf2f(uu.z), sp, bf2f(vv.z)), 0.f) * w4.z;
            p += fmaxf(fmaf(bf2f(uu.w), sp, bf2f(vv.w)), 0.f) * w4.w;
            p += __shfl_xor(p, 1);
            p += __shfl_xor(p, 2);
            p += __shfl_xor(p, 4);
            if (kk == 0) q0 = p; else if (kk == 1) q1 = p;
            else if (kk == 2) q2 = p; else q3 = p;
        }
        int srcl = (lane & 7) * 8;
        float s0 = __shfl(q0, srcl);
        float s1 = __shfl(q1, srcl);
        float s2_ = __shfl(q2, srcl);
        float s3 = __shfl(q3, srcl);
        int it = (lane >> 3) & 3;
        float q = (it == 0) ? s0 : (it == 1) ? s1 : (it == 2) ? s2_ : s3;
        q += bp;
        float ss = q * q;
#pragma unroll
        for (int off = 16; off >= 1; off >>= 1)
            ss += __shfl_xor(ss, off);
        float den = fmaxf(sqrtf(ss), 1e-12f);
        if (lane < 32) out[(size_t)n * KANCH + lane] = q / den;
    }
}

// ---------------------------------------------------------------------------
extern "C" void kernel_launch(void* const* d_in, const int* in_sizes, int n_in,
                              void* d_out, int out_size, void* d_ws, size_t ws_size,
                              hipStream_t stream)
{
    const float* feat  = (const float*)d_in[0];
    const float* dists = (const float*)d_in[1];
    const int*   src   = (const int*)d_in[2];
    const int*   dst   = (const int*)d_in[3];
    const float* w_pre = (const float*)d_in[4];
    const float* b_pre = (const float*)d_in[5];
    const float* Wu1   = (const float*)d_in[6];
    const float* bu1   = (const float*)d_in[7];
    const float* Wv1   = (const float*)d_in[8];
    const float* bv1   = (const float*)d_in[9];
    // d_in[10]=wp1, d_in[11]=bp1: layer-1 position output is discarded
    const float* Wu2   = (const float*)d_in[12];
    const float* bu2   = (const float*)d_in[13];
    const float* Wv2   = (const float*)d_in[14];
    const float* bv2   = (const float*)d_in[15];
    const float* wp2   = (const float*)d_in[16];
    const float* bp2   = (const float*)d_in[17];
    float* out = (float*)d_out;

    // workspace (~19.3 MB)
    unsigned short* wcat1 = (unsigned short*)d_ws;           // 16384 us
    float* bias1 = (float*)(wcat1 + 16384);                  // 128 f
    unsigned short* wcat2 = (unsigned short*)(bias1 + 128);  // 4096 us
    float* bias2 = (float*)(wcat2 + 4096);                   // 64 f
    unsigned short* u1s = (unsigned short*)(bias2 + 64);     // [4][NN][16]
    unsigned short* v1s = u1s + (size_t)NN * 64;             // [4][NN][16]
    unsigned short* x2b = v1s + (size_t)NN * 64;             // [NN][64]
    unsigned short* u2b = u1s;   // alias: u1s dead after gather passes
    unsigned short* v2b = v1s;   // alias: v1s dead after gather passes

    k_prep<<<81, 256, 0, stream>>>(w_pre, b_pre, Wu1, bu1, Wv1, bv1,
                                   Wu2, bu2, Wv2, bv2,
                                   wcat1, bias1, wcat2, bias2);
    k_gemm1<<<782, 256, 0, stream>>>(feat, wcat1, bias1, u1s, v1s, NN / 16);
    for (int s = 0; s < 4; ++s)
        k_gather1s<<<2048, 256, 0, stream>>>((const ushort4*)u1s, (const ushort4*)v1s,
                                             src, dst, dists, (ushort4*)x2b, s);
    k_gemm2<<<782, 256, 0, stream>>>(x2b, wcat2, bias2, u2b, v2b, NN / 16);
    k_out<<<2048, 256, 0, stream>>>((const ushort4*)u2b, (const ushort4*)v2b,
                                    src, dst, dists, wp2, bp2, out);
}

// Round 5
// 111.312 us; speedup vs baseline: 1.6289x; 1.6289x over previous
//
#include <hip/hip_runtime.h>

// PGNN: N=50000 nodes, K=32 anchors/edges per node, E=1.6M edges
// out: normalize(out_position)[N,32] f32
constexpr int NN = 50000;
constexpr int KANCH = 32;

typedef __attribute__((ext_vector_type(8))) short bfrag;   // 8 bf16 (4 VGPR)
typedef __attribute__((ext_vector_type(4))) float ffrag;   // 4 f32 acc

static __device__ __forceinline__ float bf2f(unsigned short u) {
    return __uint_as_float(((unsigned int)u) << 16);
}
static __device__ __forceinline__ unsigned short f2bf(float f) {
    unsigned int x = __float_as_uint(f);
    x += 0x7FFFu + ((x >> 16) & 1u);   // round-to-nearest-even
    return (unsigned short)(x >> 16);
}

// ---------------------------------------------------------------------------
// K0: compose layer-1 weights through the pre-linear; pack weights to bf16.
// ---------------------------------------------------------------------------
__global__ __launch_bounds__(256) void k_prep(
    const float* __restrict__ w_pre, const float* __restrict__ b_pre,
    const float* __restrict__ Wu1, const float* __restrict__ bu1,
    const float* __restrict__ Wv1, const float* __restrict__ bv1,
    const float* __restrict__ Wu2, const float* __restrict__ bu2,
    const float* __restrict__ Wv2, const float* __restrict__ bv2,
    unsigned short* __restrict__ wcat1, float* __restrict__ bias1,
    unsigned short* __restrict__ wcat2, float* __restrict__ bias2)
{
    int gid = blockIdx.x * 256 + threadIdx.x;
    if (gid < 16384) {
        int j = gid >> 7, i = gid & 127;
        const float* Wr = (j < 64) ? (Wu1 + j * 64) : (Wv1 + (j - 64) * 64);
        float a = 0.f;
        for (int t = 0; t < 64; ++t) a += Wr[t] * w_pre[t * 128 + i];
        wcat1[gid] = f2bf(a);
    } else if (gid < 16384 + 4096) {
        int g = gid - 16384;
        int j = g >> 6, i = g & 63;
        float w = (j < 32) ? Wu2[j * 64 + i] : Wv2[(j - 32) * 64 + i];
        wcat2[g] = f2bf(w);
    } else if (gid < 16384 + 4096 + 128) {
        int j = gid - (16384 + 4096);
        const float* Wr = (j < 64) ? (Wu1 + j * 64) : (Wv1 + (j - 64) * 64);
        float a = (j < 64) ? bu1[j] : bv1[j - 64];
        for (int t = 0; t < 64; ++t) a += Wr[t] * b_pre[t];
        bias1[j] = a;
    } else if (gid < 16384 + 4096 + 128 + 64) {
        int j = gid - (16384 + 4096 + 128);
        bias2[j] = (j < 32) ? bu2[j] : bv2[j - 32];
    }
}

// ---------------------------------------------------------------------------
// K1: layer-1 u/v linears via MFMA.  [NN][64] bf16 tables (round-3 verified).
// A (feat f32) split in-register into bf16 hi+lo (exact; 2 MFMAs per step).
// ---------------------------------------------------------------------------
__global__ __launch_bounds__(256) void k_gemm1(
    const float* __restrict__ feat,            // [NN][128]
    const unsigned short* __restrict__ wcat,   // [128][128] bf16
    const float* __restrict__ bias,            // [128] f32
    unsigned short* __restrict__ ub,           // [NN][64] bf16
    unsigned short* __restrict__ vb,           // [NN][64] bf16
    int nTiles)                                // NN/16
{
    __shared__ unsigned short s_w[128 * 136];  // 272 B row stride
    __shared__ float s_b[128];
    int tid = threadIdx.x;
    for (int idx = tid; idx < 128 * 16; idx += 256) {
        int r = idx >> 4, c8 = idx & 15;
        const uint4* g = reinterpret_cast<const uint4*>(wcat + r * 128 + c8 * 8);
        *reinterpret_cast<uint4*>(&s_w[r * 136 + c8 * 8]) = *g;
    }
    if (tid < 128) s_b[tid] = bias[tid];
    __syncthreads();

    int wv = __builtin_amdgcn_readfirstlane(tid >> 6);
    int lane = tid & 63;
    int col = lane & 15;        // A row (node) / D col (out) / W row
    int grp = lane >> 4;        // k-subchunk 0..3
    int slot = blockIdx.x * 4 + wv;
    int stride = gridDim.x * 4;
    for (int tile = slot; tile < nTiles; tile += stride) {
        int n0 = tile * 16;
        const float* fp = feat + (size_t)(n0 + col) * 128 + grp * 8;
        bfrag AH[4], AL[4];
#pragma unroll
        for (int s = 0; s < 4; ++s) {
            float4 p0 = *reinterpret_cast<const float4*>(fp + s * 32);
            float4 p1 = *reinterpret_cast<const float4*>(fp + s * 32 + 4);
            float a8[8] = {p0.x, p0.y, p0.z, p0.w, p1.x, p1.y, p1.z, p1.w};
#pragma unroll
            for (int e = 0; e < 8; ++e) {
                unsigned short hb = f2bf(a8[e]);
                AH[s][e] = (short)hb;
                AL[s][e] = (short)f2bf(a8[e] - bf2f(hb));
            }
        }
#pragma unroll
        for (int t = 0; t < 8; ++t) {
            ffrag a = {0.f, 0.f, 0.f, 0.f};
#pragma unroll
            for (int s = 0; s < 4; ++s) {
                const bfrag w = *reinterpret_cast<const bfrag*>(
                    &s_w[(t * 16 + col) * 136 + s * 32 + grp * 8]);
                a = __builtin_amdgcn_mfma_f32_16x16x32_bf16(AH[s], w, a, 0, 0, 0);
                a = __builtin_amdgcn_mfma_f32_16x16x32_bf16(AL[s], w, a, 0, 0, 0);
            }
            float bb = s_b[t * 16 + col];
#pragma unroll
            for (int j = 0; j < 4; ++j) {
                int node = n0 + grp * 4 + j;
                unsigned short o = f2bf(a[j] + bb);
                if (t < 4) ub[(size_t)node * 64 + t * 16 + col] = o;
                else       vb[(size_t)node * 64 + (t - 4) * 16 + col] = o;
            }
        }
    }
}

// ---------------------------------------------------------------------------
// K2: layer-1 aggregation, MLP-structured. Wave handles TWO nodes per iter;
// lane = (es=lane>>4: edge subgroup, c=lane&15: ushort4 dim chunk).
// es-major index map (k = es*8+kk): all 32 idx per node in 6 vector loads.
// ALL 32 table loads (2 nodes x 16) issued before any consumption ->
// deep vmcnt pipeline. __launch_bounds__(256,4) caps VGPR at 128.
// ---------------------------------------------------------------------------
__global__ __launch_bounds__(256, 4) void k_gather1(
    const ushort4* __restrict__ u1v, const ushort4* __restrict__ v1v, // [NN*16]
    const int* __restrict__ src, const int* __restrict__ dst,
    const float* __restrict__ dists, ushort4* __restrict__ x2v)       // [NN*16]
{
    int tid = threadIdx.x;
    int wv = __builtin_amdgcn_readfirstlane(tid >> 6);
    int lane = tid & 63;
    int c = lane & 15;      // dims 4c..4c+3
    int es = lane >> 4;     // edge subgroup 0..3 (k = es*8 + kk)
    int slot = blockIdx.x * 4 + wv;
    int stride = gridDim.x * 4;
    const int nPairs = NN / 2;
    for (int p = slot; p < nPairs; p += stride) {
        int nA = p * 2, nB = nA + 1;
        int baseA = nA * KANCH, baseB = nB * KANCH;
        // ---- index loads (es-major: each lane's 8 k's are consecutive) ----
        int4   sA0 = *reinterpret_cast<const int4*>(src + baseA + es * 8);
        int4   sA1 = *reinterpret_cast<const int4*>(src + baseA + es * 8 + 4);
        int4   dA0 = *reinterpret_cast<const int4*>(dst + baseA + es * 8);
        int4   dA1 = *reinterpret_cast<const int4*>(dst + baseA + es * 8 + 4);
        float4 pA0 = *reinterpret_cast<const float4*>(dists + baseA + es * 8);
        float4 pA1 = *reinterpret_cast<const float4*>(dists + baseA + es * 8 + 4);
        int4   sB0 = *reinterpret_cast<const int4*>(src + baseB + es * 8);
        int4   sB1 = *reinterpret_cast<const int4*>(src + baseB + es * 8 + 4);
        int4   dB0 = *reinterpret_cast<const int4*>(dst + baseB + es * 8);
        int4   dB1 = *reinterpret_cast<const int4*>(dst + baseB + es * 8 + 4);
        float4 pB0 = *reinterpret_cast<const float4*>(dists + baseB + es * 8);
        float4 pB1 = *reinterpret_cast<const float4*>(dists + baseB + es * 8 + 4);
        // ---- issue ALL table loads, then consume ----
        ushort4 uA[8], vA[8], uB[8], vB[8];
        uA[0] = u1v[(size_t)sA0.x * 16 + c]; uA[1] = u1v[(size_t)sA0.y * 16 + c];
        uA[2] = u1v[(size_t)sA0.z * 16 + c]; uA[3] = u1v[(size_t)sA0.w * 16 + c];
        uA[4] = u1v[(size_t)sA1.x * 16 + c]; uA[5] = u1v[(size_t)sA1.y * 16 + c];
        uA[6] = u1v[(size_t)sA1.z * 16 + c]; uA[7] = u1v[(size_t)sA1.w * 16 + c];
        vA[0] = v1v[(size_t)dA0.x * 16 + c]; vA[1] = v1v[(size_t)dA0.y * 16 + c];
        vA[2] = v1v[(size_t)dA0.z * 16 + c]; vA[3] = v1v[(size_t)dA0.w * 16 + c];
        vA[4] = v1v[(size_t)dA1.x * 16 + c]; vA[5] = v1v[(size_t)dA1.y * 16 + c];
        vA[6] = v1v[(size_t)dA1.z * 16 + c]; vA[7] = v1v[(size_t)dA1.w * 16 + c];
        uB[0] = u1v[(size_t)sB0.x * 16 + c]; uB[1] = u1v[(size_t)sB0.y * 16 + c];
        uB[2] = u1v[(size_t)sB0.z * 16 + c]; uB[3] = u1v[(size_t)sB0.w * 16 + c];
        uB[4] = u1v[(size_t)sB1.x * 16 + c]; uB[5] = u1v[(size_t)sB1.y * 16 + c];
        uB[6] = u1v[(size_t)sB1.z * 16 + c]; uB[7] = u1v[(size_t)sB1.w * 16 + c];
        vB[0] = v1v[(size_t)dB0.x * 16 + c]; vB[1] = v1v[(size_t)dB0.y * 16 + c];
        vB[2] = v1v[(size_t)dB0.z * 16 + c]; vB[3] = v1v[(size_t)dB0.w * 16 + c];
        vB[4] = v1v[(size_t)dB1.x * 16 + c]; vB[5] = v1v[(size_t)dB1.y * 16 + c];
        vB[6] = v1v[(size_t)dB1.z * 16 + c]; vB[7] = v1v[(size_t)dB1.w * 16 + c];

        float spA[8] = {pA0.x, pA0.y, pA0.z, pA0.w, pA1.x, pA1.y, pA1.z, pA1.w};
        float spB[8] = {pB0.x, pB0.y, pB0.z, pB0.w, pB1.x, pB1.y, pB1.z, pB1.w};
        float a0 = 0.f, a1 = 0.f, a2 = 0.f, a3 = 0.f;
        float b0 = 0.f, b1 = 0.f, b2 = 0.f, b3 = 0.f;
#pragma unroll
        for (int kk = 0; kk < 8; ++kk) {
            a0 += fmaxf(fmaf(bf2f(uA[kk].x), spA[kk], bf2f(vA[kk].x)), 0.f);
            a1 += fmaxf(fmaf(bf2f(uA[kk].y), spA[kk], bf2f(vA[kk].y)), 0.f);
            a2 += fmaxf(fmaf(bf2f(uA[kk].z), spA[kk], bf2f(vA[kk].z)), 0.f);
            a3 += fmaxf(fmaf(bf2f(uA[kk].w), spA[kk], bf2f(vA[kk].w)), 0.f);
            b0 += fmaxf(fmaf(bf2f(uB[kk].x), spB[kk], bf2f(vB[kk].x)), 0.f);
            b1 += fmaxf(fmaf(bf2f(uB[kk].y), spB[kk], bf2f(vB[kk].y)), 0.f);
            b2 += fmaxf(fmaf(bf2f(uB[kk].z), spB[kk], bf2f(vB[kk].z)), 0.f);
            b3 += fmaxf(fmaf(bf2f(uB[kk].w), spB[kk], bf2f(vB[kk].w)), 0.f);
        }
        // reduce over the 4 edge-subgroups (lane bits 4,5)
        a0 += __shfl_xor(a0, 16); a0 += __shfl_xor(a0, 32);
        a1 += __shfl_xor(a1, 16); a1 += __shfl_xor(a1, 32);
        a2 += __shfl_xor(a2, 16); a2 += __shfl_xor(a2, 32);
        a3 += __shfl_xor(a3, 16); a3 += __shfl_xor(a3, 32);
        b0 += __shfl_xor(b0, 16); b0 += __shfl_xor(b0, 32);
        b1 += __shfl_xor(b1, 16); b1 += __shfl_xor(b1, 32);
        b2 += __shfl_xor(b2, 16); b2 += __shfl_xor(b2, 32);
        b3 += __shfl_xor(b3, 16); b3 += __shfl_xor(b3, 32);
        if (lane < 16) {
            ushort4 r;
            r.x = f2bf(a0 * 0.03125f); r.y = f2bf(a1 * 0.03125f);
            r.z = f2bf(a2 * 0.03125f); r.w = f2bf(a3 * 0.03125f);
            x2v[(size_t)nA * 16 + c] = r;
        } else if (lane < 32) {
            ushort4 r;
            r.x = f2bf(b0 * 0.03125f); r.y = f2bf(b1 * 0.03125f);
            r.z = f2bf(b2 * 0.03125f); r.w = f2bf(b3 * 0.03125f);
            x2v[(size_t)nB * 16 + c] = r;
        }
    }
}

// ---------------------------------------------------------------------------
// K3: layer-2 u/v linears via MFMA.  [50000,64] bf16 @ [64,64]ᵀ bf16.
// ---------------------------------------------------------------------------
__global__ __launch_bounds__(256) void k_gemm2(
    const unsigned short* __restrict__ x2b,    // [NN][64] bf16
    const unsigned short* __restrict__ wcat,   // [64][64] bf16
    const float* __restrict__ bias,            // [64] f32
    unsigned short* __restrict__ ub,           // [NN][32] bf16
    unsigned short* __restrict__ vb,           // [NN][32] bf16
    int nTiles)
{
    __shared__ unsigned short s_w[64 * 72];
    __shared__ float s_b[64];
    int tid = threadIdx.x;
    for (int idx = tid; idx < 64 * 8; idx += 256) {
        int r = idx >> 3, c8 = idx & 7;
        const uint4* g = reinterpret_cast<const uint4*>(wcat + r * 64 + c8 * 8);
        *reinterpret_cast<uint4*>(&s_w[r * 72 + c8 * 8]) = *g;
    }
    if (tid < 64) s_b[tid] = bias[tid];
    __syncthreads();

    int wv = __builtin_amdgcn_readfirstlane(tid >> 6);
    int lane = tid & 63;
    int col = lane & 15;
    int grp = lane >> 4;
    int slot = blockIdx.x * 4 + wv;
    int stride = gridDim.x * 4;
    for (int tile = slot; tile < nTiles; tile += stride) {
        int n0 = tile * 16;
        bfrag A[2];
#pragma unroll
        for (int s = 0; s < 2; ++s) {
            uint4 raw = *reinterpret_cast<const uint4*>(
                x2b + (size_t)(n0 + col) * 64 + s * 32 + grp * 8);
            A[s] = *reinterpret_cast<const bfrag*>(&raw);
        }
#pragma unroll
        for (int t = 0; t < 4; ++t) {
            ffrag a = {0.f, 0.f, 0.f, 0.f};
#pragma unroll
            for (int s = 0; s < 2; ++s) {
                const bfrag w = *reinterpret_cast<const bfrag*>(
                    &s_w[(t * 16 + col) * 72 + s * 32 + grp * 8]);
                a = __builtin_amdgcn_mfma_f32_16x16x32_bf16(A[s], w, a, 0, 0, 0);
            }
            float bb = s_b[t * 16 + col];
#pragma unroll
            for (int j = 0; j < 4; ++j) {
                int node = n0 + grp * 4 + j;
                unsigned short o = f2bf(a[j] + bb);
                if (t < 2) ub[(size_t)node * 32 + t * 16 + col] = o;
                else       vb[(size_t)node * 32 + (t - 2) * 16 + col] = o;
            }
        }
    }
}

// ---------------------------------------------------------------------------
// K4: layer-2 message + position dot + L2 normalize, MLP-structured.
// Wave handles TWO nodes per iter; lane = (es=lane>>3, c=lane&7).
// es-major index map (k = es*4+kk): 3 vector loads per node.
// All 16 table loads issued before consumption. Norm: lanes<32 hold node A's
// 32 components, lanes>=32 node B's -> one shared 5-shfl reduce.
// ---------------------------------------------------------------------------
__global__ __launch_bounds__(256, 4) void k_out(
    const ushort4* __restrict__ u2v, const ushort4* __restrict__ v2v, // [NN*8]
    const int* __restrict__ src, const int* __restrict__ dst,
    const float* __restrict__ dists, const float* __restrict__ wp2,
    const float* __restrict__ bp2, float* __restrict__ out)
{
    int tid = threadIdx.x;
    int wv = __builtin_amdgcn_readfirstlane(tid >> 6);
    int lane = tid & 63;
    int c = lane & 7;       // dims 4c..4c+3
    int es = lane >> 3;     // edge subgroup 0..7 (k = es*4 + kk)
    int slot = blockIdx.x * 4 + wv;
    int stride = gridDim.x * 4;
    float4 w4 = reinterpret_cast<const float4*>(wp2)[c];
    float bp = bp2[0];
    const int nPairs = NN / 2;
    for (int p = slot; p < nPairs; p += stride) {
        int nA = p * 2, nB = nA + 1;
        int baseA = nA * KANCH, baseB = nB * KANCH;
        int4   sA = *reinterpret_cast<const int4*>(src + baseA + es * 4);
        int4   dA = *reinterpret_cast<const int4*>(dst + baseA + es * 4);
        float4 pA = *reinterpret_cast<const float4*>(dists + baseA + es * 4);
        int4   sB = *reinterpret_cast<const int4*>(src + baseB + es * 4);
        int4   dB = *reinterpret_cast<const int4*>(dst + baseB + es * 4);
        float4 pB = *reinterpret_cast<const float4*>(dists + baseB + es * 4);
        ushort4 uA[4], vA[4], uB[4], vB[4];
        uA[0] = u2v[(size_t)sA.x * 8 + c]; uA[1] = u2v[(size_t)sA.y * 8 + c];
        uA[2] = u2v[(size_t)sA.z * 8 + c]; uA[3] = u2v[(size_t)sA.w * 8 + c];
        vA[0] = v2v[(size_t)dA.x * 8 + c]; vA[1] = v2v[(size_t)dA.y * 8 + c];
        vA[2] = v2v[(size_t)dA.z * 8 + c]; vA[3] = v2v[(size_t)dA.w * 8 + c];
        uB[0] = u2v[(size_t)sB.x * 8 + c]; uB[1] = u2v[(size_t)sB.y * 8 + c];
        uB[2] = u2v[(size_t)sB.z * 8 + c]; uB[3] = u2v[(size_t)sB.w * 8 + c];
        vB[0] = v2v[(size_t)dB.x * 8 + c]; vB[1] = v2v[(size_t)dB.y * 8 + c];
        vB[2] = v2v[(size_t)dB.z * 8 + c]; vB[3] = v2v[(size_t)dB.w * 8 + c];
        float spA[4] = {pA.x, pA.y, pA.z, pA.w};
        float spB[4] = {pB.x, pB.y, pB.z, pB.w};
        float qA[4], qB[4];
#pragma unroll
        for (int kk = 0; kk < 4; ++kk) {
            float pa, pb;
            pa  = fmaxf(fmaf(bf2f(uA[kk].x), spA[kk], bf2f(vA[kk].x)), 0.f) * w4.x;
            pa += fmaxf(fmaf(bf2f(uA[kk].y), spA[kk], bf2f(vA[kk].y)), 0.f) * w4.y;
            pa += fmaxf(fmaf(bf2f(uA[kk].z), spA[kk], bf2f(vA[kk].z)), 0.f) * w4.z;
            pa += fmaxf(fmaf(bf2f(uA[kk].w), spA[kk], bf2f(vA[kk].w)), 0.f) * w4.w;
            pb  = fmaxf(fmaf(bf2f(uB[kk].x), spB[kk], bf2f(vB[kk].x)), 0.f) * w4.x;
            pb += fmaxf(fmaf(bf2f(uB[kk].y), spB[kk], bf2f(vB[kk].y)), 0.f) * w4.y;
            pb += fmaxf(fmaf(bf2f(uB[kk].z), spB[kk], bf2f(vB[kk].z)), 0.f) * w4.z;
            pb += fmaxf(fmaf(bf2f(uB[kk].w), spB[kk], bf2f(vB[kk].w)), 0.f) * w4.w;
            // reduce over the 8-lane dim-chunk group -> full 32-dim dot
            pa += __shfl_xor(pa, 1); pa += __shfl_xor(pa, 2); pa += __shfl_xor(pa, 4);
            pb += __shfl_xor(pb, 1); pb += __shfl_xor(pb, 2); pb += __shfl_xor(pb, 4);
            qA[kk] = pa; qB[kk] = pb;
        }
        // component t (0..31): edge k=t, es=t>>2, kk=t&3; value at lanes es*8..es*8+7
        int t = lane & 31;
        int srcl = (t >> 2) * 8;
        float cA0 = __shfl(qA[0], srcl), cA1 = __shfl(qA[1], srcl);
        float cA2 = __shfl(qA[2], srcl), cA3 = __shfl(qA[3], srcl);
        float cB0 = __shfl(qB[0], srcl), cB1 = __shfl(qB[1], srcl);
        float cB2 = __shfl(qB[2], srcl), cB3 = __shfl(qB[3], srcl);
        int ks = t & 3;
        float qa = (ks == 0) ? cA0 : (ks == 1) ? cA1 : (ks == 2) ? cA2 : cA3;
        float qb = (ks == 0) ? cB0 : (ks == 1) ? cB1 : (ks == 2) ? cB2 : cB3;
        float q = ((lane < 32) ? qa : qb) + bp;
        float ss = q * q;
#pragma unroll
        for (int off = 16; off >= 1; off >>= 1)
            ss += __shfl_xor(ss, off);     // stays within each 32-lane half
        float den = fmaxf(sqrtf(ss), 1e-12f);
        float o = q / den;
        if (lane < 32) out[(size_t)nA * KANCH + t] = o;
        else           out[(size_t)nB * KANCH + t] = o;
    }
}

// ---------------------------------------------------------------------------
extern "C" void kernel_launch(void* const* d_in, const int* in_sizes, int n_in,
                              void* d_out, int out_size, void* d_ws, size_t ws_size,
                              hipStream_t stream)
{
    const float* feat  = (const float*)d_in[0];
    const float* dists = (const float*)d_in[1];
    const int*   src   = (const int*)d_in[2];
    const int*   dst   = (const int*)d_in[3];
    const float* w_pre = (const float*)d_in[4];
    const float* b_pre = (const float*)d_in[5];
    const float* Wu1   = (const float*)d_in[6];
    const float* bu1   = (const float*)d_in[7];
    const float* Wv1   = (const float*)d_in[8];
    const float* bv1   = (const float*)d_in[9];
    // d_in[10]=wp1, d_in[11]=bp1: layer-1 position output is discarded
    const float* Wu2   = (const float*)d_in[12];
    const float* bu2   = (const float*)d_in[13];
    const float* Wv2   = (const float*)d_in[14];
    const float* bv2   = (const float*)d_in[15];
    const float* wp2   = (const float*)d_in[16];
    const float* bp2   = (const float*)d_in[17];
    float* out = (float*)d_out;

    // workspace (~19.3 MB)
    unsigned short* wcat1 = (unsigned short*)d_ws;           // 16384 us
    float* bias1 = (float*)(wcat1 + 16384);                  // 128 f
    unsigned short* wcat2 = (unsigned short*)(bias1 + 128);  // 4096 us
    float* bias2 = (float*)(wcat2 + 4096);                   // 64 f
    unsigned short* u1b = (unsigned short*)(bias2 + 64);     // [NN][64]
    unsigned short* v1b = u1b + (size_t)NN * 64;             // [NN][64]
    unsigned short* x2b = v1b + (size_t)NN * 64;             // [NN][64]
    unsigned short* u2b = u1b;   // alias: u1b dead after k_gather1
    unsigned short* v2b = v1b;   // alias: v1b dead after k_gather1

    k_prep<<<81, 256, 0, stream>>>(w_pre, b_pre, Wu1, bu1, Wv1, bv1,
                                   Wu2, bu2, Wv2, bv2,
                                   wcat1, bias1, wcat2, bias2);
    k_gemm1<<<782, 256, 0, stream>>>(feat, wcat1, bias1, u1b, v1b, NN / 16);
    k_gather1<<<2048, 256, 0, stream>>>((const ushort4*)u1b, (const ushort4*)v1b,
                                        src, dst, dists, (ushort4*)x2b);
    k_gemm2<<<782, 256, 0, stream>>>(x2b, wcat2, bias2, u2b, v2b, NN / 16);
    k_out<<<2048, 256, 0, stream>>>((const ushort4*)u2b, (const ushort4*)v2b,
                                    src, dst, dists, wp2, bp2, out);
}